// Round 5
// baseline (448.397 us; speedup 1.0000x reference)
//
#include <hip/hip_runtime.h>

typedef unsigned short u16;
typedef __attribute__((ext_vector_type(4))) float floatx4;
typedef __attribute__((ext_vector_type(8))) short short8;

#define MAXROWS 5120   // 4096 slots + 8*128 padding

__device__ __forceinline__ u16 f2bf(float f) {
    union { float f; unsigned u; } v; v.f = f;
    unsigned r = v.u + 0x7FFF + ((v.u >> 16) & 1);
    return (u16)(r >> 16);
}
__device__ __forceinline__ float bf2f(u16 h) {
    union { unsigned u; float f; } v; v.u = ((unsigned)h) << 16; return v.f;
}
__device__ __forceinline__ float silu_f(float x) { return x / (1.f + __expf(-x)); }

__device__ __forceinline__ void gl_lds16(const void* g, void* l) {
    __builtin_amdgcn_global_load_lds(
        (__attribute__((address_space(1))) unsigned int*)g,
        (__attribute__((address_space(3))) unsigned int*)l, 16, 0, 0);
}

// 8x ds_read_b128 + lgkmcnt(0) fused in one opaque asm block; MFMA consumers
// are data-dependent on the outputs so ordering is safe (issue+wait together).
__device__ __forceinline__ void ld_frags(
    unsigned a0, unsigned a1, unsigned a2, unsigned a3,
    unsigned b0, unsigned b1, unsigned b2, unsigned b3,
    short8& af0, short8& af1, short8& af2, short8& af3,
    short8& bf0, short8& bf1, short8& bf2, short8& bf3) {
    asm volatile(
        "ds_read_b128 %0, %8\n\t"
        "ds_read_b128 %1, %9\n\t"
        "ds_read_b128 %2, %10\n\t"
        "ds_read_b128 %3, %11\n\t"
        "ds_read_b128 %4, %12\n\t"
        "ds_read_b128 %5, %13\n\t"
        "ds_read_b128 %6, %14\n\t"
        "ds_read_b128 %7, %15\n\t"
        "s_waitcnt lgkmcnt(0)"
        : "=&v"(af0), "=&v"(af1), "=&v"(af2), "=&v"(af3),
          "=&v"(bf0), "=&v"(bf1), "=&v"(bf2), "=&v"(bf3)
        : "v"(a0), "v"(a1), "v"(a2), "v"(a3),
          "v"(b0), "v"(b1), "v"(b2), "v"(b3));
}

#define WAIT_VM6() __builtin_amdgcn_s_waitcnt(3958)  // vmcnt(6)
#define WAIT_VM3() __builtin_amdgcn_s_waitcnt(3955)  // vmcnt(3)
#define WAIT_VM0() __builtin_amdgcn_s_waitcnt(3952)  // vmcnt(0)
#define BAR()      __builtin_amdgcn_s_barrier()

// ---- fused: gate (blocks 0..511) + ALL fp32->bf16 weight/act conversion ----
__global__ void conv_gate(const float* __restrict__ w1, const float* __restrict__ w2,
                          const float* __restrict__ w3, const float* __restrict__ sw1,
                          const float* __restrict__ sw2, const float* __restrict__ sw3,
                          const float* __restrict__ x, const float* __restrict__ gw,
                          u16* __restrict__ W13, u16* __restrict__ W2b,
                          u16* __restrict__ S12, u16* __restrict__ S3b,
                          u16* __restrict__ Xb,
                          int* __restrict__ idxA, float* __restrict__ wA) {
    int bid = blockIdx.x;
    if (bid < 512) {  // ---- gate ----
        int w = threadIdx.x >> 6, lane = threadIdx.x & 63;
        int t = bid * 4 + w;
        const float* xr = x + (size_t)t * 1024;
        float acc[8];
#pragma unroll
        for (int e = 0; e < 8; e++) acc[e] = 0.f;
#pragma unroll
        for (int i = 0; i < 16; i++) {
            float xv = xr[lane + (i << 6)];
#pragma unroll
            for (int e = 0; e < 8; e++) acc[e] += xv * gw[e * 1024 + lane + (i << 6)];
        }
#pragma unroll
        for (int e = 0; e < 8; e++)
            for (int off = 32; off > 0; off >>= 1) acc[e] += __shfl_xor(acc[e], off);
        if (lane == 0) {
            float m = acc[0];
#pragma unroll
            for (int e = 1; e < 8; e++) m = fmaxf(m, acc[e]);
            float p[8], s = 0.f;
#pragma unroll
            for (int e = 0; e < 8; e++) { p[e] = __expf(acc[e] - m); s += p[e]; }
            float inv = 1.f / s;
#pragma unroll
            for (int e = 0; e < 8; e++) p[e] *= inv;
            int i0 = 0;
#pragma unroll
            for (int e = 1; e < 8; e++) if (p[e] > p[i0]) i0 = e;
            int i1 = (i0 == 0) ? 1 : 0;
            for (int e = i1 + 1; e < 8; e++) if (e != i0 && p[e] > p[i1]) i1 = e;
            idxA[2 * t] = i0; idxA[2 * t + 1] = i1;
            wA[2 * t] = p[i0]; wA[2 * t + 1] = p[i1];
        }
        return;
    }
    long j = (long)(bid - 512) * 256 + threadIdx.x;
    const float* src; u16* dst; long d;
    if (j < 2097152) {
        long e = j >> 18; src = w1; dst = W13; d = j + (e << 18);
    } else if ((j -= 2097152) < 2097152) {
        long e = j >> 18; src = w3; dst = W13; d = j + (e << 18) + 262144;
    } else if ((j -= 2097152) < 2097152) { src = w2;  dst = W2b; d = j; }
    else if ((j -= 2097152) < 524288) {
        long rr = j >> 8, c4 = j & 255;
        long br = ((rr >> 4) << 5) + (rr & 15);
        src = sw1; dst = S12; d = (br << 8) + c4;
    } else if ((j -= 524288) < 524288) {
        long rr = j >> 8, c4 = j & 255;
        long br = ((rr >> 4) << 5) + 16 + (rr & 15);
        src = sw2; dst = S12; d = (br << 8) + c4;
    } else if ((j -= 524288) < 524288)     { src = sw3; dst = S3b; d = j; }
    else { j -= 524288; src = x; dst = Xb; d = j; }
    float4 v = ((const float4*)src)[j];
    ushort4 o; o.x = f2bf(v.x); o.y = f2bf(v.y); o.z = f2bf(v.z); o.w = f2bf(v.w);
    ((ushort4*)dst)[d] = o;
}

// ---- single-wave deterministic rank/scatter (0 atomics), reg-preloaded ----
__global__ void rank_k(const int* __restrict__ idxA, int* __restrict__ tileexp,
                       int* __restrict__ tilem0, int* __restrict__ tilevalid,
                       int* __restrict__ ntiles, int* __restrict__ slot_of) {
    int lane = threadIdx.x;
    const int4* my4 = (const int4*)(idxA + lane * 64);
    int v[64];
#pragma unroll
    for (int k = 0; k < 16; k++) {
        int4 t4 = my4[k];
        v[4 * k] = t4.x; v[4 * k + 1] = t4.y; v[4 * k + 2] = t4.z; v[4 * k + 3] = t4.w;
    }
    int h[8];
#pragma unroll
    for (int e = 0; e < 8; e++) h[e] = 0;
#pragma unroll
    for (int i = 0; i < 64; i++) {
        int t = v[i];
#pragma unroll
        for (int e = 0; e < 8; e++) h[e] += (t == e);
    }
    int excl[8], tot[8];
#pragma unroll
    for (int e = 0; e < 8; e++) {
        int inc = h[e];
        for (int off = 1; off < 64; off <<= 1) {
            int up = __shfl_up(inc, off);
            if (lane >= off) inc += up;
        }
        excl[e] = inc - h[e];
        tot[e] = __shfl(inc, 63);
    }
    int base[8], tiles = 0;
#pragma unroll
    for (int e = 0; e < 8; e++) {
        base[e] = tiles * 128;
        tiles += (tot[e] + 127) >> 7;
    }
    if (lane == 0) {
        int t256 = 0;
        for (int e = 0; e < 8; e++) {
            int t128 = (tot[e] + 127) >> 7;
            for (int j = 0; j < t128; j += 2) {
                tileexp[t256] = e;
                tilem0[t256] = base[e] + (j << 7);
                tilevalid[t256] = ((t128 - j) >= 2) ? 256 : 128;
                t256++;
            }
        }
        ntiles[0] = t256;
    }
    int c[8];
#pragma unroll
    for (int e = 0; e < 8; e++) c[e] = base[e] + excl[e];
    int* so = slot_of + lane * 64;
#pragma unroll
    for (int i = 0; i < 64; i++) {
        int t = v[i], slot = 0;
#pragma unroll
        for (int e = 0; e < 8; e++) slot += (t == e) ? c[e] : 0;
#pragma unroll
        for (int e = 0; e < 8; e++) c[e] += (t == e);
        so[i] = slot;
    }
}

__global__ void build_xs(const float* __restrict__ x, const float* __restrict__ wA,
                         const int* __restrict__ slot_of, u16* __restrict__ XS) {
    int s = blockIdx.x, i = threadIdx.x;
    int t = s >> 1; float w = wA[s]; int slot = slot_of[s];
    float4 v = ((const float4*)(x + (size_t)t * 1024))[i];
    ushort4 o; o.x = f2bf(v.x * w); o.y = f2bf(v.y * w); o.z = f2bf(v.z * w); o.w = f2bf(v.w * w);
    ((ushort4*)(XS + (size_t)slot * 1024))[i] = o;
}

// ====== 256x128 tile, BK=32, 8 waves(4Mx2N, wave=64x64), 3 LDS bufs 72KB ======
// 2 blocks/CU (144KB LDS, 16 waves, 4 waves/SIMD) -> cross-block TLP hides
// stalls; ~544 tiles on 512 slots kills the 2-round quantization loss.
// Buffer b: A at u16 b*12288 (256x32), B at +8192 u16 (128x32). depth-2:
//   stage(t+2) issued during t (3 loads/wave); before compute(t): vmcnt(6)
//   leaves stages t+1,t+2 in flight (never 0 mid-loop); tail 3 -> 0.
// Overwrite hazard: stage(t+2) writes buf (t+2)%3 == (t-1)%3, whose reads
// finished before BAR at end of t-1; stage(t+2) is issued after that BAR.
#define STAGE3(BUF, Ab, Bb, lda, kk)                                           \
    {                                                                          \
        int rA_ = (w << 4) + rloc;                                             \
        int cgA_ = clds ^ ((rA_ >> 1) & 3);                                    \
        gl_lds16((Ab) + (size_t)(m0 + rA_) * (lda) + (kk) + (cgA_ << 3),       \
                 LDS + (BUF) * 12288 + (w << 9));                              \
        int rA2_ = rA_ + 128;                                                  \
        int cgA2_ = clds ^ ((rA2_ >> 1) & 3);                                  \
        gl_lds16((Ab) + (size_t)(m0 + rA2_) * (lda) + (kk) + (cgA2_ << 3),     \
                 LDS + (BUF) * 12288 + (w << 9) + 4096);                       \
        gl_lds16((Bb) + (size_t)(n0 + rA_) * (lda) + (kk) + (cgA_ << 3),       \
                 LDS + (BUF) * 12288 + 8192 + (w << 9));                       \
    }

#define COMPUTE(BUF)                                                           \
    {                                                                          \
        unsigned bo = (unsigned)(BUF) * 24576u;                                \
        short8 af[4], bf[4];                                                   \
        ld_frags(adA[0] + bo, adA[1] + bo, adA[2] + bo, adA[3] + bo,           \
                 adB[0] + bo, adB[1] + bo, adB[2] + bo, adB[3] + bo,           \
                 af[0], af[1], af[2], af[3], bf[0], bf[1], bf[2], bf[3]);      \
        __builtin_amdgcn_s_setprio(1);                                         \
        _Pragma("unroll")                                                      \
        for (int i_ = 0; i_ < 4; i_++)                                         \
            _Pragma("unroll")                                                  \
            for (int j_ = 0; j_ < 4; j_++)                                     \
                acc[i_][j_] = __builtin_amdgcn_mfma_f32_16x16x32_bf16(         \
                    af[i_], bf[j_], acc[i_][j_], 0, 0, 0);                     \
        __builtin_amdgcn_s_setprio(0);                                         \
    }

#define KLOOP(NSTEP, Ab, Bb, lda, kbeg)                                        \
    {                                                                          \
        STAGE3(0, Ab, Bb, lda, (kbeg));                                        \
        STAGE3(1, Ab, Bb, lda, (kbeg) + 32);                                   \
        for (int t = 0; t < (NSTEP); t++) {                                    \
            if (t + 2 < (NSTEP)) {                                             \
                STAGE3((t + 2) % 3, Ab, Bb, lda, (kbeg) + ((t + 2) << 5));     \
                WAIT_VM6();                                                    \
            } else if (t + 1 < (NSTEP)) {                                      \
                WAIT_VM3();                                                    \
            } else {                                                           \
                WAIT_VM0();                                                    \
            }                                                                  \
            BAR();                                                             \
            COMPUTE(t % 3);                                                    \
            BAR();                                                             \
        }                                                                      \
    }

#define GEMM_PRE()                                                             \
    int tid = threadIdx.x, w = tid >> 6, lane = tid & 63;                      \
    int wm = w >> 1, wn = w & 1;                                               \
    int rloc = lane >> 2, clds = lane & 3, q = lane >> 4, l15 = lane & 15;     \
    unsigned ldsbase = (unsigned)(size_t)(__attribute__((address_space(3))) u16*)LDS; \
    unsigned adA[4], adB[4];                                                   \
    _Pragma("unroll")                                                          \
    for (int i = 0; i < 4; i++) {                                              \
        int rr = (wm << 6) + (i << 4) + l15;                                   \
        int g = q ^ ((rr >> 1) & 3);                                           \
        adA[i] = ldsbase + rr * 64 + g * 16;                                   \
    }                                                                          \
    _Pragma("unroll")                                                          \
    for (int j = 0; j < 4; j++) {                                              \
        int rr = (wn << 6) + (j << 4) + l15;                                   \
        int g = q ^ ((rr >> 1) & 3);                                           \
        adB[j] = ldsbase + 16384 + rr * 64 + g * 16;                           \
    }                                                                          \
    floatx4 acc[4][4];                                                         \
    _Pragma("unroll")                                                          \
    for (int i = 0; i < 4; i++)                                                \
        _Pragma("unroll")                                                      \
        for (int j = 0; j < 4; j++) {                                          \
            floatx4 z = {0.f, 0.f, 0.f, 0.f}; acc[i][j] = z;                   \
        }

// ---- stage-A GEMM: routed (XS@W13) + shared (Xb@S12), 256x128 tiles ----
// bid<640: routed mt=bid>>4 (<=40), nt=bid&15. bid>=640: shared 8x32.
__global__ __launch_bounds__(512, 4) void gemm_A(
    const u16* __restrict__ XS, const u16* __restrict__ Xb,
    const u16* __restrict__ W13, const u16* __restrict__ S12,
    const float* __restrict__ b1, const float* __restrict__ b3,
    u16* __restrict__ H, u16* __restrict__ X3h, u16* __restrict__ G,
    const int* __restrict__ tileexp, const int* __restrict__ tilem0,
    const int* __restrict__ tilevalid, const int* __restrict__ ntiles) {
    __shared__ u16 LDS[36864];
    int bid = blockIdx.x;
    const u16 *Ab, *Bb; int m0, n0, nt = 0, e = 0, vcnt = 256; bool routed;
    if (bid < 640) {
        routed = true;
        int mt = bid >> 4;
        nt = bid & 15;
        if (mt >= ntiles[0]) return;
        e = tileexp[mt]; m0 = tilem0[mt]; vcnt = tilevalid[mt];
        n0 = nt << 7;
        Ab = XS; Bb = W13 + ((size_t)e << 21);
    } else {
        routed = false; int s = bid - 640;
        m0 = (s >> 5) << 8; n0 = (s & 31) << 7;
        Ab = Xb; Bb = S12;
    }
    GEMM_PRE();

    KLOOP(32, Ab, Bb, 1024, 0);

    if (routed) {
#pragma unroll
        for (int i = 0; i < 4; i++) {
            if (((wm << 6) + (i << 4)) >= vcnt) continue;
            int rowb = m0 + (wm << 6) + (i << 4) + (q << 2);
#pragma unroll
            for (int j = 0; j < 4; j++) {
                int col = n0 + (wn << 6) + (j << 4) + l15;
#pragma unroll
                for (int r = 0; r < 4; r++) {
                    float v = acc[i][j][r];
                    int rw = rowb + r;
                    if (nt < 8) {
                        H[(size_t)rw * 1024 + col] = f2bf(silu_f(v + b1[e * 1024 + col]));
                    } else {
                        int c2 = col - 1024;
                        X3h[(size_t)rw * 1024 + c2] = f2bf(v + b3[e * 1024 + c2]);
                    }
                }
            }
        }
    } else {
#pragma unroll
        for (int i = 0; i < 4; i++) {
            int rowb = m0 + (wm << 6) + (i << 4) + (q << 2);
#pragma unroll
            for (int jp = 0; jp < 4; jp += 2) {
                int brb = n0 + (wn << 6) + (jp << 4);
                int lcol = ((brb >> 5) << 4) + l15;
#pragma unroll
                for (int r = 0; r < 4; r++) {
                    float u = acc[i][jp][r], v = acc[i][jp + 1][r];
                    G[(size_t)(rowb + r) * 2048 + lcol] = f2bf(silu_f(u) * v);
                }
            }
        }
    }
}

// ---- stage-B GEMM: routed (H@W2, splitK2) + shared (G@S3b, splitK4) ----
// bid<640: routed mt=bid>>4, nt=(bid&15)&7, kc=(bid&15)>>3.
// bid>=640: shared s: m0=(s>>5)<<8, n0=((s&31)>>2)<<7, kc=s&3.
__global__ __launch_bounds__(512, 4) void gemm_B(
    const u16* __restrict__ H, const u16* __restrict__ G,
    const u16* __restrict__ W2b, const u16* __restrict__ S3b,
    const float* __restrict__ b2, const u16* __restrict__ X3h,
    u16* __restrict__ P0, u16* __restrict__ P1, float* __restrict__ Z,
    const int* __restrict__ tileexp, const int* __restrict__ tilem0,
    const int* __restrict__ tilevalid, const int* __restrict__ ntiles) {
    __shared__ u16 LDS[36864];
    int bid = blockIdx.x;
    const u16 *Ab, *Bb; int m0, n0, kc, kbeg, lda, e = 0, vcnt = 256; bool routed;
    if (bid < 640) {
        routed = true;
        int mt = bid >> 4;
        int r = bid & 15; int nt = r & 7; kc = r >> 3;
        if (mt >= ntiles[0]) return;
        e = tileexp[mt]; m0 = tilem0[mt]; vcnt = tilevalid[mt];
        n0 = nt << 7;
        Ab = H; Bb = W2b + ((size_t)e << 20); lda = 1024; kbeg = kc << 9;
    } else {
        routed = false; int s = bid - 640;
        m0 = (s >> 5) << 8; n0 = ((s & 31) >> 2) << 7; kc = s & 3;
        Ab = G; Bb = S3b; lda = 2048; kbeg = kc << 9;
    }
    GEMM_PRE();

    KLOOP(16, Ab, Bb, lda, kbeg);

    if (routed) {
        u16* Pk = kc ? P1 : P0;
#pragma unroll
        for (int i = 0; i < 4; i++) {
            if (((wm << 6) + (i << 4)) >= vcnt) continue;
            int rowb = m0 + (wm << 6) + (i << 4) + (q << 2);
#pragma unroll
            for (int j = 0; j < 4; j++) {
                int col = n0 + (wn << 6) + (j << 4) + l15;
#pragma unroll
                for (int r = 0; r < 4; r++) {
                    int rw = rowb + r;
                    float v = acc[i][j][r] + (kc == 0 ? b2[e * 1024 + col] : 0.f);
                    float pv = v * bf2f(X3h[(size_t)rw * 1024 + col]);
                    Pk[(size_t)rw * 1024 + col] = f2bf(pv);
                }
            }
        }
    } else {
        float* Zk = Z + (size_t)kc * 2097152;
#pragma unroll
        for (int i = 0; i < 4; i++) {
            int rowb = m0 + (wm << 6) + (i << 4) + (q << 2);
#pragma unroll
            for (int j = 0; j < 4; j++) {
                int col = n0 + (wn << 6) + (j << 4) + l15;
#pragma unroll
                for (int r = 0; r < 4; r++)
                    Zk[(size_t)(rowb + r) * 1024 + col] = acc[i][j][r];
            }
        }
    }
}

__global__ void final_k(const float* __restrict__ Z,
                        const u16* __restrict__ P0, const u16* __restrict__ P1,
                        const int* __restrict__ slot_of, float* __restrict__ out) {
    int i = blockIdx.x * 256 + threadIdx.x;
    int t = i >> 8, c4 = i & 255;
    int s0 = slot_of[2 * t], s1 = slot_of[2 * t + 1];
    size_t zi = (size_t)t * 256 + c4;
    float4 z0 = ((const float4*)Z)[zi];
    float4 z1 = ((const float4*)(Z + 2097152))[zi];
    float4 z2 = ((const float4*)(Z + 4194304))[zi];
    float4 z3 = ((const float4*)(Z + 6291456))[zi];
    ushort4 a0 = ((const ushort4*)P0)[(size_t)s0 * 256 + c4];
    ushort4 a1 = ((const ushort4*)P1)[(size_t)s0 * 256 + c4];
    ushort4 c0 = ((const ushort4*)P0)[(size_t)s1 * 256 + c4];
    ushort4 c1 = ((const ushort4*)P1)[(size_t)s1 * 256 + c4];
    float4 o;
    o.x = z0.x + z1.x + z2.x + z3.x + bf2f(a0.x) + bf2f(a1.x) + bf2f(c0.x) + bf2f(c1.x);
    o.y = z0.y + z1.y + z2.y + z3.y + bf2f(a0.y) + bf2f(a1.y) + bf2f(c0.y) + bf2f(c1.y);
    o.z = z0.z + z1.z + z2.z + z3.z + bf2f(a0.z) + bf2f(a1.z) + bf2f(c0.z) + bf2f(c1.z);
    o.w = z0.w + z1.w + z2.w + z3.w + bf2f(a0.w) + bf2f(a1.w) + bf2f(c0.w) + bf2f(c1.w);
    ((float4*)out)[(size_t)t * 256 + c4] = o;
}

extern "C" void kernel_launch(void* const* d_in, const int* in_sizes, int n_in,
                              void* d_out, int out_size, void* d_ws, size_t ws_size,
                              hipStream_t stream) {
    const float* x   = (const float*)d_in[0];
    const float* gw  = (const float*)d_in[1];
    const float* w1  = (const float*)d_in[2];
    const float* b1  = (const float*)d_in[3];
    const float* w2  = (const float*)d_in[4];
    const float* b2  = (const float*)d_in[5];
    const float* w3  = (const float*)d_in[6];
    const float* b3  = (const float*)d_in[7];
    const float* sw1 = (const float*)d_in[8];
    const float* sw2 = (const float*)d_in[9];
    const float* sw3 = (const float*)d_in[10];
    float* out = (float*)d_out;

    char* p = (char*)d_ws;
    int* ntiles    = (int*)(p + 192);
    int* tileexp   = (int*)(p + 256);
    int* tilem0    = (int*)(p + 512);
    int* tilevalid = (int*)(p + 768);
    size_t off = 4096;
    u16*   XS      = (u16*)(p + off);   off += (size_t)MAXROWS * 1024 * 2;
    int*   idxA    = (int*)(p + off);   off += 16384;
    float* wA      = (float*)(p + off); off += 16384;
    int*   slot_of = (int*)(p + off);   off += 16384;
    u16*   H       = (u16*)(p + off);   off += (size_t)MAXROWS * 1024 * 2;
    u16*   X3h     = (u16*)(p + off);   off += (size_t)MAXROWS * 1024 * 2;
    u16*   P0      = (u16*)(p + off);   off += (size_t)MAXROWS * 1024 * 2;
    u16*   P1      = (u16*)(p + off);   off += (size_t)MAXROWS * 1024 * 2;
    float* Z       = (float*)(p + off); off += (size_t)4 * 2048 * 1024 * 4;
    u16*   W13     = (u16*)(p + off);   off += (size_t)8 * 2048 * 1024 * 2;
    u16*   W2b     = (u16*)(p + off);   off += (size_t)8 * 1024 * 1024 * 2;
    u16*   S12     = (u16*)(p + off);   off += (size_t)4096 * 1024 * 2;
    u16*   S3b     = (u16*)(p + off);   off += (size_t)1024 * 2048 * 2;
    u16*   Xb      = (u16*)(p + off);   off += (size_t)2048 * 1024 * 2;
    u16*   G       = (u16*)(p + off);   off += (size_t)2048 * 2048 * 2;

    conv_gate<<<33280, 256, 0, stream>>>(w1, w2, w3, sw1, sw2, sw3, x, gw,
                                         W13, W2b, S12, S3b, Xb, idxA, wA);
    rank_k<<<1, 64, 0, stream>>>(idxA, tileexp, tilem0, tilevalid, ntiles, slot_of);
    build_xs<<<4096, 256, 0, stream>>>(x, wA, slot_of, XS);

    gemm_A<<<896, 512, 0, stream>>>(XS, Xb, W13, S12, b1, b3, H, X3h, G,
                                    tileexp, tilem0, tilevalid, ntiles);
    gemm_B<<<896, 512, 0, stream>>>(H, G, W2b, S3b, b2, X3h, P0, P1, Z,
                                    tileexp, tilem0, tilevalid, ntiles);
    final_k<<<2048, 256, 0, stream>>>(Z, P0, P1, slot_of, out);
}

// Round 6
// 290.677 us; speedup vs baseline: 1.5426x; 1.5426x over previous
//
#include <hip/hip_runtime.h>

typedef unsigned short u16;
typedef __attribute__((ext_vector_type(4))) float floatx4;
typedef __attribute__((ext_vector_type(8))) short short8;

#define MAXROWS 5120   // 4096 slots + 8*128 padding

__device__ __forceinline__ u16 f2bf(float f) {
    union { float f; unsigned u; } v; v.f = f;
    unsigned r = v.u + 0x7FFF + ((v.u >> 16) & 1);
    return (u16)(r >> 16);
}
__device__ __forceinline__ float bf2f(u16 h) {
    union { unsigned u; float f; } v; v.u = ((unsigned)h) << 16; return v.f;
}
__device__ __forceinline__ float silu_f(float x) { return x / (1.f + __expf(-x)); }

__device__ __forceinline__ void gl_lds16(const void* g, void* l) {
    __builtin_amdgcn_global_load_lds(
        (__attribute__((address_space(1))) unsigned int*)g,
        (__attribute__((address_space(3))) unsigned int*)l, 16, 0, 0);
}

// 8x ds_read_b128 + lgkmcnt(0) fused in one opaque asm block; MFMA consumers
// are data-dependent on the outputs so ordering is safe (issue+wait together).
__device__ __forceinline__ void ld_frags(
    unsigned a0, unsigned a1, unsigned a2, unsigned a3,
    unsigned b0, unsigned b1, unsigned b2, unsigned b3,
    short8& af0, short8& af1, short8& af2, short8& af3,
    short8& bf0, short8& bf1, short8& bf2, short8& bf3) {
    asm volatile(
        "ds_read_b128 %0, %8\n\t"
        "ds_read_b128 %1, %9\n\t"
        "ds_read_b128 %2, %10\n\t"
        "ds_read_b128 %3, %11\n\t"
        "ds_read_b128 %4, %12\n\t"
        "ds_read_b128 %5, %13\n\t"
        "ds_read_b128 %6, %14\n\t"
        "ds_read_b128 %7, %15\n\t"
        "s_waitcnt lgkmcnt(0)"
        : "=&v"(af0), "=&v"(af1), "=&v"(af2), "=&v"(af3),
          "=&v"(bf0), "=&v"(bf1), "=&v"(bf2), "=&v"(bf3)
        : "v"(a0), "v"(a1), "v"(a2), "v"(a3),
          "v"(b0), "v"(b1), "v"(b2), "v"(b3));
}

#define WAIT_VM6() __builtin_amdgcn_s_waitcnt(3958)  // vmcnt(6)
#define WAIT_VM3() __builtin_amdgcn_s_waitcnt(3955)  // vmcnt(3)
#define WAIT_VM0() __builtin_amdgcn_s_waitcnt(3952)  // vmcnt(0)
#define BAR()      __builtin_amdgcn_s_barrier()

// ---- fused: gate (blocks 0..511) + ALL fp32->bf16 weight/act conversion ----
__global__ void conv_gate(const float* __restrict__ w1, const float* __restrict__ w2,
                          const float* __restrict__ w3, const float* __restrict__ sw1,
                          const float* __restrict__ sw2, const float* __restrict__ sw3,
                          const float* __restrict__ x, const float* __restrict__ gw,
                          u16* __restrict__ W13, u16* __restrict__ W2b,
                          u16* __restrict__ S12, u16* __restrict__ S3b,
                          u16* __restrict__ Xb,
                          int* __restrict__ idxA, float* __restrict__ wA) {
    int bid = blockIdx.x;
    if (bid < 512) {  // ---- gate ----
        int w = threadIdx.x >> 6, lane = threadIdx.x & 63;
        int t = bid * 4 + w;
        const float* xr = x + (size_t)t * 1024;
        float acc[8];
#pragma unroll
        for (int e = 0; e < 8; e++) acc[e] = 0.f;
#pragma unroll
        for (int i = 0; i < 16; i++) {
            float xv = xr[lane + (i << 6)];
#pragma unroll
            for (int e = 0; e < 8; e++) acc[e] += xv * gw[e * 1024 + lane + (i << 6)];
        }
#pragma unroll
        for (int e = 0; e < 8; e++)
            for (int off = 32; off > 0; off >>= 1) acc[e] += __shfl_xor(acc[e], off);
        if (lane == 0) {
            float m = acc[0];
#pragma unroll
            for (int e = 1; e < 8; e++) m = fmaxf(m, acc[e]);
            float p[8], s = 0.f;
#pragma unroll
            for (int e = 0; e < 8; e++) { p[e] = __expf(acc[e] - m); s += p[e]; }
            float inv = 1.f / s;
#pragma unroll
            for (int e = 0; e < 8; e++) p[e] *= inv;
            int i0 = 0;
#pragma unroll
            for (int e = 1; e < 8; e++) if (p[e] > p[i0]) i0 = e;
            int i1 = (i0 == 0) ? 1 : 0;
            for (int e = i1 + 1; e < 8; e++) if (e != i0 && p[e] > p[i1]) i1 = e;
            idxA[2 * t] = i0; idxA[2 * t + 1] = i1;
            wA[2 * t] = p[i0]; wA[2 * t + 1] = p[i1];
        }
        return;
    }
    long j = (long)(bid - 512) * 256 + threadIdx.x;
    const float* src; u16* dst; long d;
    if (j < 2097152) {
        long e = j >> 18; src = w1; dst = W13; d = j + (e << 18);
    } else if ((j -= 2097152) < 2097152) {
        long e = j >> 18; src = w3; dst = W13; d = j + (e << 18) + 262144;
    } else if ((j -= 2097152) < 2097152) { src = w2;  dst = W2b; d = j; }
    else if ((j -= 2097152) < 524288) {
        long rr = j >> 8, c4 = j & 255;
        long br = ((rr >> 4) << 5) + (rr & 15);
        src = sw1; dst = S12; d = (br << 8) + c4;
    } else if ((j -= 524288) < 524288) {
        long rr = j >> 8, c4 = j & 255;
        long br = ((rr >> 4) << 5) + 16 + (rr & 15);
        src = sw2; dst = S12; d = (br << 8) + c4;
    } else if ((j -= 524288) < 524288)     { src = sw3; dst = S3b; d = j; }
    else { j -= 524288; src = x; dst = Xb; d = j; }
    float4 v = ((const float4*)src)[j];
    ushort4 o; o.x = f2bf(v.x); o.y = f2bf(v.y); o.z = f2bf(v.z); o.w = f2bf(v.w);
    ((ushort4*)dst)[d] = o;
}

// ---- single-wave deterministic rank/scatter (0 atomics) ----
// int4 loads processed component-wise: NO per-thread big array (rule #20 —
// the R5 v[64] version spilled to scratch: VGPR=64, 165us).
__global__ void rank_k(const int* __restrict__ idxA, int* __restrict__ tileexp,
                       int* __restrict__ tilem0, int* __restrict__ tilevalid,
                       int* __restrict__ ntiles, int* __restrict__ slot_of) {
    int lane = threadIdx.x;
    const int4* my4 = (const int4*)(idxA + lane * 64);
    int h[8];
#pragma unroll
    for (int e = 0; e < 8; e++) h[e] = 0;
    for (int k = 0; k < 16; k++) {
        int4 t = my4[k];
#pragma unroll
        for (int e = 0; e < 8; e++)
            h[e] += (t.x == e) + (t.y == e) + (t.z == e) + (t.w == e);
    }
    int excl[8], tot[8];
#pragma unroll
    for (int e = 0; e < 8; e++) {
        int inc = h[e];
        for (int off = 1; off < 64; off <<= 1) {
            int up = __shfl_up(inc, off);
            if (lane >= off) inc += up;
        }
        excl[e] = inc - h[e];
        tot[e] = __shfl(inc, 63);
    }
    int base[8], tiles = 0;
#pragma unroll
    for (int e = 0; e < 8; e++) {
        base[e] = tiles * 128;
        tiles += (tot[e] + 127) >> 7;
    }
    if (lane == 0) {
        int t256 = 0;
        for (int e = 0; e < 8; e++) {
            int t128 = (tot[e] + 127) >> 7;
            for (int j = 0; j < t128; j += 2) {
                tileexp[t256] = e;
                tilem0[t256] = base[e] + (j << 7);
                tilevalid[t256] = ((t128 - j) >= 2) ? 256 : 128;
                t256++;
            }
        }
        ntiles[0] = t256;
    }
    int c[8];
#pragma unroll
    for (int e = 0; e < 8; e++) c[e] = base[e] + excl[e];
    int4* so4 = (int4*)(slot_of + lane * 64);
    for (int k = 0; k < 16; k++) {
        int4 t = my4[k];
        int4 s;
        int sx = 0;
#pragma unroll
        for (int e = 0; e < 8; e++) sx += (t.x == e) ? c[e] : 0;
#pragma unroll
        for (int e = 0; e < 8; e++) c[e] += (t.x == e);
        int sy = 0;
#pragma unroll
        for (int e = 0; e < 8; e++) sy += (t.y == e) ? c[e] : 0;
#pragma unroll
        for (int e = 0; e < 8; e++) c[e] += (t.y == e);
        int sz = 0;
#pragma unroll
        for (int e = 0; e < 8; e++) sz += (t.z == e) ? c[e] : 0;
#pragma unroll
        for (int e = 0; e < 8; e++) c[e] += (t.z == e);
        int sw = 0;
#pragma unroll
        for (int e = 0; e < 8; e++) sw += (t.w == e) ? c[e] : 0;
#pragma unroll
        for (int e = 0; e < 8; e++) c[e] += (t.w == e);
        s.x = sx; s.y = sy; s.z = sz; s.w = sw;
        so4[k] = s;
    }
}

__global__ void build_xs(const float* __restrict__ x, const float* __restrict__ wA,
                         const int* __restrict__ slot_of, u16* __restrict__ XS) {
    int s = blockIdx.x, i = threadIdx.x;
    int t = s >> 1; float w = wA[s]; int slot = slot_of[s];
    float4 v = ((const float4*)(x + (size_t)t * 1024))[i];
    ushort4 o; o.x = f2bf(v.x * w); o.y = f2bf(v.y * w); o.z = f2bf(v.z * w); o.w = f2bf(v.w * w);
    ((ushort4*)(XS + (size_t)slot * 1024))[i] = o;
}

// ====== 256x128 tile, BK=32, 8 waves(4Mx2N, wave=64x64), 3 LDS bufs 72KB ======
// 2 blocks/CU (144KB LDS, 16 waves, 4 waves/SIMD) -> cross-block TLP hides
// stalls. Buffer b: A at u16 b*12288 (256x32), B at +8192 u16 (128x32).
// depth-2: stage(t+2) issued during t (3 loads/wave); before compute(t):
// vmcnt(6) leaves stages t+1,t+2 in flight (never 0 mid-loop); tail 3 -> 0.
// Overwrite hazard: stage(t+2) writes buf (t+2)%3 == (t-1)%3, whose reads
// finished before BAR at end of t-1; stage(t+2) is issued after that BAR.
#define STAGE3(BUF, Ab, Bb, lda, kk)                                           \
    {                                                                          \
        int rA_ = (w << 4) + rloc;                                             \
        int cgA_ = clds ^ ((rA_ >> 1) & 3);                                    \
        gl_lds16((Ab) + (size_t)(m0 + rA_) * (lda) + (kk) + (cgA_ << 3),       \
                 LDS + (BUF) * 12288 + (w << 9));                              \
        int rA2_ = rA_ + 128;                                                  \
        int cgA2_ = clds ^ ((rA2_ >> 1) & 3);                                  \
        gl_lds16((Ab) + (size_t)(m0 + rA2_) * (lda) + (kk) + (cgA2_ << 3),     \
                 LDS + (BUF) * 12288 + (w << 9) + 4096);                       \
        gl_lds16((Bb) + (size_t)(n0 + rA_) * (lda) + (kk) + (cgA_ << 3),       \
                 LDS + (BUF) * 12288 + 8192 + (w << 9));                       \
    }

#define COMPUTE(BUF)                                                           \
    {                                                                          \
        unsigned bo = (unsigned)(BUF) * 24576u;                                \
        short8 af[4], bf[4];                                                   \
        ld_frags(adA[0] + bo, adA[1] + bo, adA[2] + bo, adA[3] + bo,           \
                 adB[0] + bo, adB[1] + bo, adB[2] + bo, adB[3] + bo,           \
                 af[0], af[1], af[2], af[3], bf[0], bf[1], bf[2], bf[3]);      \
        __builtin_amdgcn_s_setprio(1);                                         \
        _Pragma("unroll")                                                      \
        for (int i_ = 0; i_ < 4; i_++)                                         \
            _Pragma("unroll")                                                  \
            for (int j_ = 0; j_ < 4; j_++)                                     \
                acc[i_][j_] = __builtin_amdgcn_mfma_f32_16x16x32_bf16(         \
                    af[i_], bf[j_], acc[i_][j_], 0, 0, 0);                     \
        __builtin_amdgcn_s_setprio(0);                                         \
    }

#define KLOOP(NSTEP, Ab, Bb, lda, kbeg)                                        \
    {                                                                          \
        STAGE3(0, Ab, Bb, lda, (kbeg));                                        \
        STAGE3(1, Ab, Bb, lda, (kbeg) + 32);                                   \
        for (int t = 0; t < (NSTEP); t++) {                                    \
            if (t + 2 < (NSTEP)) {                                             \
                STAGE3((t + 2) % 3, Ab, Bb, lda, (kbeg) + ((t + 2) << 5));     \
                WAIT_VM6();                                                    \
            } else if (t + 1 < (NSTEP)) {                                      \
                WAIT_VM3();                                                    \
            } else {                                                           \
                WAIT_VM0();                                                    \
            }                                                                  \
            BAR();                                                             \
            COMPUTE(t % 3);                                                    \
            BAR();                                                             \
        }                                                                      \
    }

#define GEMM_PRE()                                                             \
    int tid = threadIdx.x, w = tid >> 6, lane = tid & 63;                      \
    int wm = w >> 1, wn = w & 1;                                               \
    int rloc = lane >> 2, clds = lane & 3, q = lane >> 4, l15 = lane & 15;     \
    unsigned ldsbase = (unsigned)(size_t)(__attribute__((address_space(3))) u16*)LDS; \
    unsigned adA[4], adB[4];                                                   \
    _Pragma("unroll")                                                          \
    for (int i = 0; i < 4; i++) {                                              \
        int rr = (wm << 6) + (i << 4) + l15;                                   \
        int g = q ^ ((rr >> 1) & 3);                                           \
        adA[i] = ldsbase + rr * 64 + g * 16;                                   \
    }                                                                          \
    _Pragma("unroll")                                                          \
    for (int j = 0; j < 4; j++) {                                              \
        int rr = (wn << 6) + (j << 4) + l15;                                   \
        int g = q ^ ((rr >> 1) & 3);                                           \
        adB[j] = ldsbase + 16384 + rr * 64 + g * 16;                           \
    }                                                                          \
    floatx4 acc[4][4];                                                         \
    _Pragma("unroll")                                                          \
    for (int i = 0; i < 4; i++)                                                \
        _Pragma("unroll")                                                      \
        for (int j = 0; j < 4; j++) {                                          \
            floatx4 z = {0.f, 0.f, 0.f, 0.f}; acc[i][j] = z;                   \
        }

// ---- stage-A GEMM: routed (XS@W13) + shared (Xb@S12), 256x128 tiles ----
// bid<640: routed mt=bid>>4 (<=40), nt=bid&15. bid>=640: shared 8x32.
__global__ __launch_bounds__(512, 4) void gemm_A(
    const u16* __restrict__ XS, const u16* __restrict__ Xb,
    const u16* __restrict__ W13, const u16* __restrict__ S12,
    const float* __restrict__ b1, const float* __restrict__ b3,
    u16* __restrict__ H, u16* __restrict__ X3h, u16* __restrict__ G,
    const int* __restrict__ tileexp, const int* __restrict__ tilem0,
    const int* __restrict__ tilevalid, const int* __restrict__ ntiles) {
    __shared__ u16 LDS[36864];
    int bid = blockIdx.x;
    const u16 *Ab, *Bb; int m0, n0, nt = 0, e = 0, vcnt = 256; bool routed;
    if (bid < 640) {
        routed = true;
        int mt = bid >> 4;
        nt = bid & 15;
        if (mt >= ntiles[0]) return;
        e = tileexp[mt]; m0 = tilem0[mt]; vcnt = tilevalid[mt];
        n0 = nt << 7;
        Ab = XS; Bb = W13 + ((size_t)e << 21);
    } else {
        routed = false; int s = bid - 640;
        m0 = (s >> 5) << 8; n0 = (s & 31) << 7;
        Ab = Xb; Bb = S12;
    }
    GEMM_PRE();

    KLOOP(32, Ab, Bb, 1024, 0);

    if (routed) {
#pragma unroll
        for (int i = 0; i < 4; i++) {
            if (((wm << 6) + (i << 4)) >= vcnt) continue;
            int rowb = m0 + (wm << 6) + (i << 4) + (q << 2);
#pragma unroll
            for (int j = 0; j < 4; j++) {
                int col = n0 + (wn << 6) + (j << 4) + l15;
#pragma unroll
                for (int r = 0; r < 4; r++) {
                    float v = acc[i][j][r];
                    int rw = rowb + r;
                    if (nt < 8) {
                        H[(size_t)rw * 1024 + col] = f2bf(silu_f(v + b1[e * 1024 + col]));
                    } else {
                        int c2 = col - 1024;
                        X3h[(size_t)rw * 1024 + c2] = f2bf(v + b3[e * 1024 + c2]);
                    }
                }
            }
        }
    } else {
#pragma unroll
        for (int i = 0; i < 4; i++) {
            int rowb = m0 + (wm << 6) + (i << 4) + (q << 2);
#pragma unroll
            for (int jp = 0; jp < 4; jp += 2) {
                int brb = n0 + (wn << 6) + (jp << 4);
                int lcol = ((brb >> 5) << 4) + l15;
#pragma unroll
                for (int r = 0; r < 4; r++) {
                    float u = acc[i][jp][r], v = acc[i][jp + 1][r];
                    G[(size_t)(rowb + r) * 2048 + lcol] = f2bf(silu_f(u) * v);
                }
            }
        }
    }
}

// ---- stage-B GEMM: routed (H@W2, splitK2) + shared (G@S3b, splitK2) ----
// bid<640: routed mt=bid>>4, nt=(bid&15)&7, kc=(bid&15)>>3, 16 K-steps.
// bid>=640: shared s=bid-640 in [0,128): m0=(s>>4)<<8, n0=((s&15)>>1)<<7,
//           kc=s&1, kbeg=kc<<10, 32 K-steps. 288+128=416 blocks -> 1 round.
__global__ __launch_bounds__(512, 4) void gemm_B(
    const u16* __restrict__ H, const u16* __restrict__ G,
    const u16* __restrict__ W2b, const u16* __restrict__ S3b,
    const float* __restrict__ b2, const u16* __restrict__ X3h,
    u16* __restrict__ P0, u16* __restrict__ P1, float* __restrict__ Z,
    const int* __restrict__ tileexp, const int* __restrict__ tilem0,
    const int* __restrict__ tilevalid, const int* __restrict__ ntiles) {
    __shared__ u16 LDS[36864];
    int bid = blockIdx.x;
    const u16 *Ab, *Bb; int m0, n0, kc, kbeg, lda, np, e = 0, vcnt = 256; bool routed;
    if (bid < 640) {
        routed = true;
        int mt = bid >> 4;
        int r = bid & 15; int nt = r & 7; kc = r >> 3;
        if (mt >= ntiles[0]) return;
        e = tileexp[mt]; m0 = tilem0[mt]; vcnt = tilevalid[mt];
        n0 = nt << 7;
        Ab = H; Bb = W2b + ((size_t)e << 20); lda = 1024; kbeg = kc << 9; np = 16;
    } else {
        routed = false; int s = bid - 640;
        m0 = (s >> 4) << 8; n0 = ((s & 15) >> 1) << 7; kc = s & 1;
        Ab = G; Bb = S3b; lda = 2048; kbeg = kc << 10; np = 32;
    }
    GEMM_PRE();

    KLOOP(np, Ab, Bb, lda, kbeg);

    if (routed) {
        u16* Pk = kc ? P1 : P0;
#pragma unroll
        for (int i = 0; i < 4; i++) {
            if (((wm << 6) + (i << 4)) >= vcnt) continue;
            int rowb = m0 + (wm << 6) + (i << 4) + (q << 2);
#pragma unroll
            for (int j = 0; j < 4; j++) {
                int col = n0 + (wn << 6) + (j << 4) + l15;
#pragma unroll
                for (int r = 0; r < 4; r++) {
                    int rw = rowb + r;
                    float v = acc[i][j][r] + (kc == 0 ? b2[e * 1024 + col] : 0.f);
                    float pv = v * bf2f(X3h[(size_t)rw * 1024 + col]);
                    Pk[(size_t)rw * 1024 + col] = f2bf(pv);
                }
            }
        }
    } else {
        float* Zk = Z + (size_t)kc * 2097152;
#pragma unroll
        for (int i = 0; i < 4; i++) {
            int rowb = m0 + (wm << 6) + (i << 4) + (q << 2);
#pragma unroll
            for (int j = 0; j < 4; j++) {
                int col = n0 + (wn << 6) + (j << 4) + l15;
#pragma unroll
                for (int r = 0; r < 4; r++)
                    Zk[(size_t)(rowb + r) * 1024 + col] = acc[i][j][r];
            }
        }
    }
}

__global__ void final_k(const float* __restrict__ Z,
                        const u16* __restrict__ P0, const u16* __restrict__ P1,
                        const int* __restrict__ slot_of, float* __restrict__ out) {
    int i = blockIdx.x * 256 + threadIdx.x;
    int t = i >> 8, c4 = i & 255;
    int s0 = slot_of[2 * t], s1 = slot_of[2 * t + 1];
    size_t zi = (size_t)t * 256 + c4;
    float4 z0 = ((const float4*)Z)[zi];
    float4 z1 = ((const float4*)(Z + 2097152))[zi];
    ushort4 a0 = ((const ushort4*)P0)[(size_t)s0 * 256 + c4];
    ushort4 a1 = ((const ushort4*)P1)[(size_t)s0 * 256 + c4];
    ushort4 c0 = ((const ushort4*)P0)[(size_t)s1 * 256 + c4];
    ushort4 c1 = ((const ushort4*)P1)[(size_t)s1 * 256 + c4];
    float4 o;
    o.x = z0.x + z1.x + bf2f(a0.x) + bf2f(a1.x) + bf2f(c0.x) + bf2f(c1.x);
    o.y = z0.y + z1.y + bf2f(a0.y) + bf2f(a1.y) + bf2f(c0.y) + bf2f(c1.y);
    o.z = z0.z + z1.z + bf2f(a0.z) + bf2f(a1.z) + bf2f(c0.z) + bf2f(c1.z);
    o.w = z0.w + z1.w + bf2f(a0.w) + bf2f(a1.w) + bf2f(c0.w) + bf2f(c1.w);
    ((float4*)out)[(size_t)t * 256 + c4] = o;
}

extern "C" void kernel_launch(void* const* d_in, const int* in_sizes, int n_in,
                              void* d_out, int out_size, void* d_ws, size_t ws_size,
                              hipStream_t stream) {
    const float* x   = (const float*)d_in[0];
    const float* gw  = (const float*)d_in[1];
    const float* w1  = (const float*)d_in[2];
    const float* b1  = (const float*)d_in[3];
    const float* w2  = (const float*)d_in[4];
    const float* b2  = (const float*)d_in[5];
    const float* w3  = (const float*)d_in[6];
    const float* b3  = (const float*)d_in[7];
    const float* sw1 = (const float*)d_in[8];
    const float* sw2 = (const float*)d_in[9];
    const float* sw3 = (const float*)d_in[10];
    float* out = (float*)d_out;

    char* p = (char*)d_ws;
    int* ntiles    = (int*)(p + 192);
    int* tileexp   = (int*)(p + 256);
    int* tilem0    = (int*)(p + 512);
    int* tilevalid = (int*)(p + 768);
    size_t off = 4096;
    u16*   XS      = (u16*)(p + off);   off += (size_t)MAXROWS * 1024 * 2;
    int*   idxA    = (int*)(p + off);   off += 16384;
    float* wA      = (float*)(p + off); off += 16384;
    int*   slot_of = (int*)(p + off);   off += 16384;
    u16*   H       = (u16*)(p + off);   off += (size_t)MAXROWS * 1024 * 2;
    u16*   X3h     = (u16*)(p + off);   off += (size_t)MAXROWS * 1024 * 2;
    u16*   P0      = (u16*)(p + off);   off += (size_t)MAXROWS * 1024 * 2;
    u16*   P1      = (u16*)(p + off);   off += (size_t)MAXROWS * 1024 * 2;
    float* Z       = (float*)(p + off); off += (size_t)4 * 2048 * 1024 * 4;
    u16*   W13     = (u16*)(p + off);   off += (size_t)8 * 2048 * 1024 * 2;
    u16*   W2b     = (u16*)(p + off);   off += (size_t)8 * 1024 * 1024 * 2;
    u16*   S12     = (u16*)(p + off);   off += (size_t)4096 * 1024 * 2;
    u16*   S3b     = (u16*)(p + off);   off += (size_t)1024 * 2048 * 2;
    u16*   Xb      = (u16*)(p + off);   off += (size_t)2048 * 1024 * 2;
    u16*   G       = (u16*)(p + off);   off += (size_t)2048 * 2048 * 2;

    conv_gate<<<33280, 256, 0, stream>>>(w1, w2, w3, sw1, sw2, sw3, x, gw,
                                         W13, W2b, S12, S3b, Xb, idxA, wA);
    rank_k<<<1, 64, 0, stream>>>(idxA, tileexp, tilem0, tilevalid, ntiles, slot_of);
    build_xs<<<4096, 256, 0, stream>>>(x, wA, slot_of, XS);

    gemm_A<<<896, 512, 0, stream>>>(XS, Xb, W13, S12, b1, b3, H, X3h, G,
                                    tileexp, tilem0, tilevalid, ntiles);
    gemm_B<<<768, 512, 0, stream>>>(H, G, W2b, S3b, b2, X3h, P0, P1, Z,
                                    tileexp, tilem0, tilevalid, ntiles);
    final_k<<<2048, 256, 0, stream>>>(Z, P0, P1, slot_of, out);
}